// Round 6
// baseline (553.225 us; speedup 1.0000x reference)
//
#include <hip/hip_runtime.h>
#include <hip/hip_bf16.h>
#include <math.h>

#define NN 512

typedef __attribute__((ext_vector_type(8))) short short8;
typedef __attribute__((ext_vector_type(4))) float f32x4;

__device__ __forceinline__ float selu_f(float x) {
    const float sc = 1.0507009873554805f, al = 1.6732632423543772f;
    return x > 0.f ? sc * x : sc * al * expm1f(x);
}
__device__ __forceinline__ unsigned short f2b(float f) {
    unsigned int u = __float_as_uint(f);
    unsigned int r = (u + 0x7fffu + ((u >> 16) & 1u)) >> 16;
    return (unsigned short)r;
}
__device__ __forceinline__ float b2f(unsigned short h) {
    return __uint_as_float(((unsigned int)h) << 16);
}
__device__ __forceinline__ float ulo(unsigned int u) {
    return __uint_as_float(u << 16);
}
__device__ __forceinline__ float uhi(unsigned int u) {
    return __uint_as_float(u & 0xffff0000u);
}
__device__ __forceinline__ unsigned int pk2(float a, float b) {
    return (unsigned int)f2b(a) | ((unsigned int)f2b(b) << 16);
}
__device__ __forceinline__ void gload16(const void* g, void* l) {
    __builtin_amdgcn_global_load_lds(
        (const __attribute__((address_space(1))) unsigned int*)g,
        (__attribute__((address_space(3))) unsigned int*)l, 16, 0, 0);
}
__device__ __forceinline__ float wred(float x) {
    x += __shfl_xor(x, 1, 64);
    x += __shfl_xor(x, 2, 64);
    x += __shfl_xor(x, 4, 64);
    x += __shfl_xor(x, 8, 64);
    x += __shfl_xor(x, 16, 64);
    x += __shfl_xor(x, 32, 64);
    return x;
}

// ---------------- graph construction (f32) ----------------

__global__ __launch_bounds__(64) void nodevec_kernel(
    const float* __restrict__ emb, const float* __restrict__ lw,
    const float* __restrict__ lb, float* __restrict__ nv) {
    int i = blockIdx.x, j = threadIdx.x;
    __shared__ float e_s[64];
    e_s[j] = emb[i * 64 + j];
    __syncthreads();
    float acc = lb[j];
    for (int k = 0; k < 64; k++) acc += e_s[k] * lw[j * 64 + k];
    nv[i * 64 + j] = tanhf(3.0f * acc);
}

__global__ __launch_bounds__(512) void adjacency_kernel(
    const float* __restrict__ nv1, const float* __restrict__ nv2,
    float* __restrict__ adj) {
    int v = blockIdx.x, w = threadIdx.x;
    __shared__ float a1s[64], a2s[64];
    if (threadIdx.x < 64) {
        a1s[threadIdx.x] = nv1[v * 64 + threadIdx.x];
        a2s[threadIdx.x] = nv2[v * 64 + threadIdx.x];
    }
    __syncthreads();
    float acc = 0.f;
    for (int k = 0; k < 64; k++) {
        acc += a1s[k] * nv2[w * 64 + k];
        acc -= a2s[k] * nv1[w * 64 + k];
    }
    adj[v * NN + w] = selu_f(tanhf(3.0f * acc));
}

__global__ __launch_bounds__(256) void topk_kernel(
    float* __restrict__ adj, float* __restrict__ rowsump) {
    __shared__ float orig[512], srt[512];
    __shared__ unsigned char keep[512];
    __shared__ float red[256];
    int v = blockIdx.x, t = threadIdx.x;
    orig[t] = adj[v * NN + t];
    orig[t + 256] = adj[v * NN + t + 256];
    srt[t] = orig[t];
    srt[t + 256] = orig[t + 256];
    __syncthreads();
    for (int k = 2; k <= 512; k <<= 1) {
        for (int j = k >> 1; j > 0; j >>= 1) {
            for (int pass = 0; pass < 2; ++pass) {
                int i = t + pass * 256;
                int ixj = i ^ j;
                if (ixj > i) {
                    bool up = ((i & k) == 0);
                    float a = srt[i], b = srt[ixj];
                    if ((a > b) == up) { srt[i] = b; srt[ixj] = a; }
                }
            }
            __syncthreads();
        }
    }
    float thr = srt[256];
    if (t == 0) {
        int g = 0;
        for (int i = 0; i < 512; i++) if (srt[i] > thr) g++;
        int quota = 256 - g;
        for (int w = 0; w < 512; w++) {
            float x = orig[w];
            bool kp = false;
            if (x > thr) kp = true;
            else if (x == thr && quota > 0) { kp = true; quota--; }
            keep[w] = kp ? 1 : 0;
        }
    }
    __syncthreads();
    float part = 0.f;
    for (int pass = 0; pass < 2; pass++) {
        int w = t + pass * 256;
        float val = keep[w] ? orig[w] : 0.0f;
        adj[v * NN + w] = val;
        part += val;
    }
    red[t] = part;
    __syncthreads();
    if (t < 128) red[t] += red[t + 128];
    __syncthreads();
    if (t < 64) {
        float x = red[t] + red[t + 64];
        for (int m = 32; m; m >>= 1) x += __shfl_xor(x, m, 64);
        if (t == 0) rowsump[v] = x + 1.0f;
    }
}

__global__ __launch_bounds__(256) void colsum_kernel(
    const float* __restrict__ adp, float* __restrict__ colsum) {
    int w = blockIdx.x * 256 + threadIdx.x;
    float s = 0.f;
    for (int v = 0; v < NN; v++) s += adp[v * NN + w];
    colsum[w] = s;
}

// adjacency stored hi/lo split: aT[w][0..511]=hi, aT[w][512..1023]=lo
__global__ __launch_bounds__(256) void normalize_kernel(
    const float* __restrict__ adp, const float* __restrict__ rowsump,
    const float* __restrict__ colsum, unsigned short* __restrict__ a1T,
    unsigned short* __restrict__ a2T) {
    int w = blockIdx.x;
    for (int v = threadIdx.x; v < NN; v += 256) {
        float d = (v == w) ? 1.0f : 0.0f;
        float f1 = (adp[v * NN + w] + d) / rowsump[v];
        float f2 = (adp[w * NN + v] + d) / (colsum[v] + 1.0f);
        unsigned short h1 = f2b(f1), h2 = f2b(f2);
        a1T[w * 1024 + v] = h1;
        a1T[w * 1024 + 512 + v] = f2b(f1 - b2f(h1));
        a2T[w * 1024 + v] = h2;
        a2T[w * 1024 + 512 + v] = f2b(f2 - b2f(h2));
    }
}

// ---------------- main pipeline ----------------
// h storage: [j=(n,c,l)][1024] bf16; cols 0..511 = hi, 512..1023 = lo.

__global__ __launch_bounds__(256) void start_kernel(
    const float* __restrict__ x, const float* __restrict__ sw,
    const float* __restrict__ sb, unsigned int* __restrict__ h_u) {
    int n = blockIdx.x >> 6, l = blockIdx.x & 63;
    int t = threadIdx.x;
    float x0 = x[(n * 512 + 2 * t) * 64 + l];
    float x1 = x[(n * 512 + 2 * t + 1) * 64 + l];
#pragma unroll
    for (int c = 0; c < 32; c++) {
        float wc = sw[c], bc = sb[c];
        float f0 = x0 * wc + bc;
        float f1 = x1 * wc + bc;
        unsigned short h0 = f2b(f0), h1 = f2b(f1);
        float l0 = f0 - b2f(h0), l1 = f1 - b2f(h1);
        int j = (n * 32 + c) * 64 + l;
        h_u[j * 512 + t] = (unsigned int)h0 | ((unsigned int)h1 << 16);
        h_u[j * 512 + 256 + t] = pk2(l0, l1);
    }
}

// dst(j,w) = 0.05*base(j,w) + 0.95 * sum_v value(j,v)*a[v][w]
// Compensated K=1536: A''=[h_hi|h_lo|h_hi], B''=[a_hi;a_hi;a_lo].
// BM=128 BN=64 BK=64, grid(64,8), 256 thr. Double-buffered LDS, XOR swizzle.
__global__ __launch_bounds__(256) void prop_mfma(
    const unsigned short* __restrict__ H, const unsigned short* __restrict__ base,
    const unsigned short* __restrict__ AT, unsigned short* __restrict__ dst) {
    __shared__ __align__(16) short At[2][128 * 64];  // 32 KB
    __shared__ __align__(16) short Bt[2][64 * 64];   // 16 KB
    int t = threadIdx.x;
    int lane = t & 63;
    int wid = t >> 6;
    int wm = wid >> 1, wn = wid & 1;
    int j0 = blockIdx.x << 7;
    int w0 = blockIdx.y << 6;
    f32x4 acc[4][2];
#pragma unroll
    for (int m = 0; m < 4; m++)
#pragma unroll
        for (int n = 0; n < 2; n++) acc[m][n] = (f32x4)0.f;

    int l15 = lane & 15;
    int lhi = lane >> 4;
    int rsw = l15 & 7;

#define STAGE(tk, bufi)                                                     \
    {                                                                       \
        int kk = (tk) << 6;                                                 \
        int ca = (kk < 1024) ? kk : (kk - 1024);                            \
        int cb = (kk < 512) ? kk : (kk - 512);                              \
        _Pragma("unroll") for (int it = 0; it < 4; it++) {                  \
            int slot = it * 256 + t;                                        \
            int r = slot >> 3, sl = slot & 7;                               \
            gload16(H + (j0 + r) * 1024 + ca + ((sl ^ (r & 7)) << 3),       \
                    &At[bufi][slot * 8]);                                   \
        }                                                                   \
        _Pragma("unroll") for (int it = 0; it < 2; it++) {                  \
            int slot = it * 256 + t;                                        \
            int r = slot >> 3, sl = slot & 7;                               \
            gload16(AT + (w0 + r) * 1024 + cb + ((sl ^ (r & 7)) << 3),      \
                    &Bt[bufi][slot * 8]);                                   \
        }                                                                   \
    }

    STAGE(0, 0);
    __syncthreads();
    for (int tk = 0; tk < 24; tk++) {
        int cb_ = tk & 1;
        if (tk < 23) STAGE(tk + 1, cb_ ^ 1);
#pragma unroll
        for (int kh = 0; kh < 2; kh++) {
            int soff = ((kh * 4 + lhi) ^ rsw) << 3;
            short8 a[4], b[2];
#pragma unroll
            for (int m = 0; m < 4; m++)
                a[m] = *(const short8*)&At[cb_][(wm * 64 + m * 16 + l15) * 64 +
                                               soff];
#pragma unroll
            for (int n = 0; n < 2; n++)
                b[n] = *(const short8*)&Bt[cb_][(wn * 32 + n * 16 + l15) * 64 +
                                               soff];
#pragma unroll
            for (int m = 0; m < 4; m++)
#pragma unroll
                for (int n = 0; n < 2; n++)
                    acc[m][n] = __builtin_amdgcn_mfma_f32_16x16x32_bf16(
                        a[m], b[n], acc[m][n], 0, 0, 0);
        }
        __syncthreads();
    }
#undef STAGE
    // C/D: col = lane&15, row = (lane>>4)*4 + reg
#pragma unroll
    for (int m = 0; m < 4; m++) {
#pragma unroll
        for (int n = 0; n < 2; n++) {
#pragma unroll
            for (int r = 0; r < 4; r++) {
                int row = j0 + wm * 64 + m * 16 + lhi * 4 + r;
                int col = w0 + wn * 32 + n * 16 + l15;
                int ih = row * 1024 + col;
                float bf = b2f(base[ih]) + b2f(base[ih + 512]);
                float f = 0.05f * bf + 0.95f * acc[m][n][r];
                unsigned short hi = f2b(f);
                dst[ih] = hi;
                dst[ih + 512] = f2b(f - b2f(hi));
            }
        }
    }
}

// dst[n][o][l][v] (+)= b[o] + sum_c h0*W[o,c] + h1*W[o,c+32] + h2*W[o,c+64]
template <int ACCUM>
__global__ __launch_bounds__(256) void chanmix_kernel(
    const unsigned int* __restrict__ h0, const unsigned int* __restrict__ h1,
    const unsigned int* __restrict__ h2, const float* __restrict__ w,
    const float* __restrict__ b, unsigned int* __restrict__ dst_u) {
    __shared__ float ws[32 * 96];
    int bid = blockIdx.x;
    int vc = bid & 3, l = (bid >> 2) & 63, n = bid >> 8;
    int t = threadIdx.x;
    int vl = t & 63, q = t >> 6;
    for (int i = t; i < 32 * 96; i += 256) ws[i] = w[i];
    __syncthreads();
    float acc[8][2];
#pragma unroll
    for (int oo = 0; oo < 8; oo++) {
        float bb = b[q * 8 + oo];
        acc[oo][0] = bb;
        acc[oo][1] = bb;
    }
    int uoff = vc * 64 + vl;
    for (int c = 0; c < 32; c++) {
        int j = (n * 32 + c) * 64 + l;
        unsigned int h0h = h0[j * 512 + uoff], h0l = h0[j * 512 + 256 + uoff];
        unsigned int h1h = h1[j * 512 + uoff], h1l = h1[j * 512 + 256 + uoff];
        unsigned int h2h = h2[j * 512 + uoff], h2l = h2[j * 512 + 256 + uoff];
        float x0l = ulo(h0h) + ulo(h0l), x0h = uhi(h0h) + uhi(h0l);
        float x1l = ulo(h1h) + ulo(h1l), x1h = uhi(h1h) + uhi(h1l);
        float x2l = ulo(h2h) + ulo(h2l), x2h = uhi(h2h) + uhi(h2l);
#pragma unroll
        for (int oo = 0; oo < 8; oo++) {
            int o = q * 8 + oo;
            float w0c = ws[o * 96 + c];
            float w1c = ws[o * 96 + 32 + c];
            float w2c = ws[o * 96 + 64 + c];
            acc[oo][0] += x0l * w0c + x1l * w1c + x2l * w2c;
            acc[oo][1] += x0h * w0c + x1h * w1c + x2h * w2c;
        }
    }
#pragma unroll
    for (int oo = 0; oo < 8; oo++) {
        int o = q * 8 + oo;
        int j = (n * 32 + o) * 64 + l;
        float a0 = acc[oo][0], a1 = acc[oo][1];
        if (ACCUM) {
            unsigned int oh = dst_u[j * 512 + uoff];
            unsigned int ol = dst_u[j * 512 + 256 + uoff];
            a0 += ulo(oh) + ulo(ol);
            a1 += uhi(oh) + uhi(ol);
        }
        unsigned short hi0 = f2b(a0), hi1 = f2b(a1);
        float lo0 = a0 - b2f(hi0), lo1 = a1 - b2f(hi1);
        dst_u[j * 512 + uoff] = (unsigned int)hi0 | ((unsigned int)hi1 << 16);
        dst_u[j * 512 + 256 + uoff] = pk2(lo0, lo1);
    }
}

// LayerNorm#1 (over l) + transpose to v-major: ht[(n*512+v)][c*64+l] packed
// uint32 (hi | lo<<16). grid = n(4) x c(32) x vb(8) = 1024 blocks, 256 thr.
__global__ __launch_bounds__(256) void lnt_kernel(
    const unsigned short* __restrict__ h, const float* __restrict__ lw,
    const float* __restrict__ lb, unsigned int* __restrict__ ht) {
    __shared__ float th[64][65];
    __shared__ unsigned int tt[64][65];
    __shared__ float p1s[4][64], p2s[4][64], ms[64], is[64];
    int b = blockIdx.x;
    int c = b & 31, vb = (b >> 5) & 7, n = b >> 8;
    int t = threadIdx.x;
#pragma unroll
    for (int half = 0; half < 2; half++) {
        int s = half * 256 + t;
        int l = s >> 3, q = s & 7;
        const unsigned short* p =
            h + (size_t)((n * 32 + c) * 64 + l) * 1024 + vb * 64 + q * 8;
        short8 hiv = *(const short8*)p;
        short8 lov = *(const short8*)(p + 512);
#pragma unroll
        for (int i = 0; i < 8; i++)
            th[l][q * 8 + i] =
                b2f((unsigned short)hiv[i]) + b2f((unsigned short)lov[i]);
    }
    __syncthreads();
    {
        int v = t & 63, g = t >> 6;
        float s = 0.f, sq = 0.f;
#pragma unroll
        for (int i = 0; i < 16; i++) {
            float f = th[g * 16 + i][v];
            s += f;
            sq += f * f;
        }
        p1s[g][v] = s;
        p2s[g][v] = sq;
    }
    __syncthreads();
    if (t < 64) {
        float s = p1s[0][t] + p1s[1][t] + p1s[2][t] + p1s[3][t];
        float sq = p2s[0][t] + p2s[1][t] + p2s[2][t] + p2s[3][t];
        float m = s * (1.f / 64.f);
        float var = fmaxf(sq * (1.f / 64.f) - m * m, 0.f);
        ms[t] = m;
        is[t] = 1.f / sqrtf(var + 1e-12f);
    }
    __syncthreads();
    {
        int v = t & 63, g = t >> 6;
        float m = ms[v], inv = is[v];
#pragma unroll
        for (int i = 0; i < 16; i++) {
            int l = g * 16 + i;
            float f = lw[l] * (th[l][v] - m) * inv + lb[l];
            unsigned short hi = f2b(f);
            tt[v][l] = (unsigned int)hi | ((unsigned int)f2b(f - b2f(hi)) << 16);
        }
    }
    __syncthreads();
    {
        int vr = t >> 2, ch = t & 3;
        unsigned int* dstp =
            ht + (size_t)(n * 512 + vb * 64 + vr) * 2048 + c * 64 + ch * 16;
#pragma unroll
        for (int i = 0; i < 4; i++) {
            uint4 val;
            val.x = tt[vr][ch * 16 + i * 4 + 0];
            val.y = tt[vr][ch * 16 + i * 4 + 1];
            val.z = tt[vr][ch * 16 + i * 4 + 2];
            val.w = tt[vr][ch * 16 + i * 4 + 3];
            *(uint4*)(dstp + i * 4) = val;
        }
    }
}

// fused end1+selu+end2+LN#2+sum-over-o2. Block per (n,v): 2048 blocks x 256.
// e1 lives in LDS (f32), per-lane state tiny -> no spills, high occupancy.
__global__ __launch_bounds__(256) void end_block(
    const unsigned int* __restrict__ ht, const float* __restrict__ w1,
    const float* __restrict__ b1, const float* __restrict__ w2,
    const float* __restrict__ b2, const float* __restrict__ lw,
    const float* __restrict__ lb, float* __restrict__ out) {
    __shared__ float w1s[64 * 32];   // 8 KB [o1][c]
    __shared__ float w2s[64 * 64];   // 16 KB [o2][o1]
    __shared__ float hv_s[32][64];   // 8 KB [c][l]
    __shared__ float e1s[64][64];    // 16 KB [o1][l]
    __shared__ float b1s[64], b2s[64], lws[64], lbs[64];
    __shared__ float reds[4][64];
    int t = threadIdx.x;
    int n = blockIdx.x >> 9, v = blockIdx.x & 511;
    for (int i = t; i < 2048; i += 256) w1s[i] = w1[i];
    for (int i = t; i < 4096; i += 256) w2s[i] = w2[i];
    if (t < 64) {
        b1s[t] = b1[t];
        b2s[t] = b2[t];
        lws[t] = lw[t];
        lbs[t] = lb[t];
    }
    const unsigned int* row = ht + (size_t)(n * 512 + v) * 2048;
#pragma unroll
    for (int k = 0; k < 8; k++) {
        int i = k * 256 + t;
        int c = i >> 6, l = i & 63;
        unsigned int u = row[i];
        hv_s[c][l] = ulo(u) + uhi(u);
    }
    __syncthreads();
    int wv = t >> 6, lane = t & 63;
#pragma unroll
    for (int oo = 0; oo < 16; oo++) {
        int o1 = wv * 16 + oo;
        float a = b1s[o1];
#pragma unroll
        for (int c = 0; c < 32; c++) a += w1s[o1 * 32 + c] * hv_s[c][lane];
        e1s[o1][lane] = selu_f(a);
    }
    __syncthreads();
    float accout = 0.f;
    float lwl = lws[lane], lbl = lbs[lane];
#pragma unroll
    for (int oo = 0; oo < 16; oo++) {
        int o2 = wv * 16 + oo;
        float e2 = b2s[o2];
#pragma unroll
        for (int o1 = 0; o1 < 64; o1++) e2 += w2s[o2 * 64 + o1] * e1s[o1][lane];
        float m = wred(e2) * (1.f / 64.f);
        float d = e2 - m;
        float q = wred(d * d);
        float inv = 1.f / sqrtf(q * (1.f / 64.f) + 1e-12f);
        accout += lwl * d * inv + lbl;
    }
    reds[wv][lane] = accout;
    __syncthreads();
    if (t < 64) {
        out[(n * 64 + t) * 512 + v] =
            reds[0][t] + reds[1][t] + reds[2][t] + reds[3][t];
    }
}

// ---------------- launch ----------------

extern "C" void kernel_launch(void* const* d_in, const int* in_sizes, int n_in,
                              void* d_out, int out_size, void* d_ws,
                              size_t ws_size, hipStream_t stream) {
    const float* x = (const float*)d_in[0];
    const float* emb1 = (const float*)d_in[1];
    const float* emb2 = (const float*)d_in[2];
    const float* lin1_w = (const float*)d_in[3];
    const float* lin1_b = (const float*)d_in[4];
    const float* lin2_w = (const float*)d_in[5];
    const float* lin2_b = (const float*)d_in[6];
    const float* start_w = (const float*)d_in[7];
    const float* start_b = (const float*)d_in[8];
    const float* g1_w = (const float*)d_in[9];
    const float* g1_b = (const float*)d_in[10];
    const float* g2_w = (const float*)d_in[11];
    const float* g2_b = (const float*)d_in[12];
    const float* ln_w = (const float*)d_in[13];
    const float* ln_b = (const float*)d_in[14];
    const float* end1_w = (const float*)d_in[15];
    const float* end1_b = (const float*)d_in[16];
    const float* end2_w = (const float*)d_in[17];
    const float* end2_b = (const float*)d_in[18];
    float* out = (float*)d_out;

    char* ws = (char*)d_ws;
    float* nv1 = (float*)(ws + 0);
    float* nv2 = (float*)(ws + 131072);
    float* adp = (float*)(ws + 262144);                     // 1 MB f32
    unsigned short* a1T = (unsigned short*)(ws + 1310720);  // 1 MB hi/lo
    unsigned short* a2T = (unsigned short*)(ws + 2359296);  // 1 MB hi/lo
    float* rowsump = (float*)(ws + 3407872);
    float* colsum = (float*)(ws + 3409920);
    unsigned short* hA = (unsigned short*)(ws + 4194304);   // 16 MB split
    unsigned short* hB = (unsigned short*)(ws + 20971520);  // 16 MB
    unsigned short* p1 = (unsigned short*)(ws + 37748736);  // 16 MB
    unsigned short* p2 = (unsigned short*)(ws + 54525952);  // 16 MB

    nodevec_kernel<<<512, 64, 0, stream>>>(emb1, lin1_w, lin1_b, nv1);
    nodevec_kernel<<<512, 64, 0, stream>>>(emb2, lin2_w, lin2_b, nv2);
    adjacency_kernel<<<512, 512, 0, stream>>>(nv1, nv2, adp);
    topk_kernel<<<512, 256, 0, stream>>>(adp, rowsump);
    colsum_kernel<<<2, 256, 0, stream>>>(adp, colsum);
    normalize_kernel<<<512, 256, 0, stream>>>(adp, rowsump, colsum, a1T, a2T);

    start_kernel<<<256, 256, 0, stream>>>(x, start_w, start_b, (unsigned int*)hA);

    dim3 pgrid(64, 8);
    unsigned short* cur = hA;
    unsigned short* nxt = hB;
    for (int layer = 0; layer < 2; layer++) {
        const float* w1 = g1_w + layer * 32 * 96;
        const float* bb1 = g1_b + layer * 32;
        const float* w2 = g2_w + layer * 32 * 96;
        const float* bb2 = g2_b + layer * 32;
        prop_mfma<<<pgrid, 256, 0, stream>>>(cur, cur, a1T, p1);
        prop_mfma<<<pgrid, 256, 0, stream>>>(p1, cur, a1T, p2);
        chanmix_kernel<0><<<1024, 256, 0, stream>>>(
            (const unsigned int*)cur, (const unsigned int*)p1,
            (const unsigned int*)p2, w1, bb1, (unsigned int*)nxt);
        prop_mfma<<<pgrid, 256, 0, stream>>>(cur, cur, a2T, p1);
        prop_mfma<<<pgrid, 256, 0, stream>>>(p1, cur, a2T, p2);
        chanmix_kernel<1><<<1024, 256, 0, stream>>>(
            (const unsigned int*)cur, (const unsigned int*)p1,
            (const unsigned int*)p2, w2, bb2, (unsigned int*)nxt);
        unsigned short* tmp = cur;
        cur = nxt;
        nxt = tmp;
    }

    lnt_kernel<<<1024, 256, 0, stream>>>(cur, ln_w, ln_b, (unsigned int*)p1);
    end_block<<<2048, 256, 0, stream>>>((const unsigned int*)p1, end1_w, end1_b,
                                        end2_w, end2_b, ln_w, ln_b, out);
}

// Round 7
// 435.290 us; speedup vs baseline: 1.2709x; 1.2709x over previous
//
#include <hip/hip_runtime.h>
#include <hip/hip_bf16.h>
#include <math.h>

#define NN 512

typedef __attribute__((ext_vector_type(8))) short short8;
typedef __attribute__((ext_vector_type(4))) float f32x4;

__device__ __forceinline__ float selu_f(float x) {
    const float sc = 1.0507009873554805f, al = 1.6732632423543772f;
    return x > 0.f ? sc * x : sc * al * expm1f(x);
}
__device__ __forceinline__ unsigned short f2b(float f) {
    unsigned int u = __float_as_uint(f);
    unsigned int r = (u + 0x7fffu + ((u >> 16) & 1u)) >> 16;
    return (unsigned short)r;
}
__device__ __forceinline__ float b2f(unsigned short h) {
    return __uint_as_float(((unsigned int)h) << 16);
}
__device__ __forceinline__ float ulo(unsigned int u) {
    return __uint_as_float(u << 16);
}
__device__ __forceinline__ float uhi(unsigned int u) {
    return __uint_as_float(u & 0xffff0000u);
}
__device__ __forceinline__ unsigned int pk2(float a, float b) {
    return (unsigned int)f2b(a) | ((unsigned int)f2b(b) << 16);
}
__device__ __forceinline__ void gload16(const void* g, void* l) {
    __builtin_amdgcn_global_load_lds(
        (const __attribute__((address_space(1))) unsigned int*)g,
        (__attribute__((address_space(3))) unsigned int*)l, 16, 0, 0);
}

// ---------------- graph construction (f32) ----------------

__global__ __launch_bounds__(64) void nodevec_kernel(
    const float* __restrict__ emb, const float* __restrict__ lw,
    const float* __restrict__ lb, float* __restrict__ nv) {
    int i = blockIdx.x, j = threadIdx.x;
    __shared__ float e_s[64];
    e_s[j] = emb[i * 64 + j];
    __syncthreads();
    float acc = lb[j];
    for (int k = 0; k < 64; k++) acc += e_s[k] * lw[j * 64 + k];
    nv[i * 64 + j] = tanhf(3.0f * acc);
}

__global__ __launch_bounds__(512) void adjacency_kernel(
    const float* __restrict__ nv1, const float* __restrict__ nv2,
    float* __restrict__ adj) {
    int v = blockIdx.x, w = threadIdx.x;
    __shared__ float a1s[64], a2s[64];
    if (threadIdx.x < 64) {
        a1s[threadIdx.x] = nv1[v * 64 + threadIdx.x];
        a2s[threadIdx.x] = nv2[v * 64 + threadIdx.x];
    }
    __syncthreads();
    float acc = 0.f;
    for (int k = 0; k < 64; k++) {
        acc += a1s[k] * nv2[w * 64 + k];
        acc -= a2s[k] * nv1[w * 64 + k];
    }
    adj[v * NN + w] = selu_f(tanhf(3.0f * acc));
}

__global__ __launch_bounds__(256) void topk_kernel(
    float* __restrict__ adj, float* __restrict__ rowsump) {
    __shared__ float orig[512], srt[512];
    __shared__ unsigned char keep[512];
    __shared__ float red[256];
    int v = blockIdx.x, t = threadIdx.x;
    orig[t] = adj[v * NN + t];
    orig[t + 256] = adj[v * NN + t + 256];
    srt[t] = orig[t];
    srt[t + 256] = orig[t + 256];
    __syncthreads();
    for (int k = 2; k <= 512; k <<= 1) {
        for (int j = k >> 1; j > 0; j >>= 1) {
            for (int pass = 0; pass < 2; ++pass) {
                int i = t + pass * 256;
                int ixj = i ^ j;
                if (ixj > i) {
                    bool up = ((i & k) == 0);
                    float a = srt[i], b = srt[ixj];
                    if ((a > b) == up) { srt[i] = b; srt[ixj] = a; }
                }
            }
            __syncthreads();
        }
    }
    float thr = srt[256];
    if (t == 0) {
        int g = 0;
        for (int i = 0; i < 512; i++) if (srt[i] > thr) g++;
        int quota = 256 - g;
        for (int w = 0; w < 512; w++) {
            float x = orig[w];
            bool kp = false;
            if (x > thr) kp = true;
            else if (x == thr && quota > 0) { kp = true; quota--; }
            keep[w] = kp ? 1 : 0;
        }
    }
    __syncthreads();
    float part = 0.f;
    for (int pass = 0; pass < 2; pass++) {
        int w = t + pass * 256;
        float val = keep[w] ? orig[w] : 0.0f;
        adj[v * NN + w] = val;
        part += val;
    }
    red[t] = part;
    __syncthreads();
    if (t < 128) red[t] += red[t + 128];
    __syncthreads();
    if (t < 64) {
        float x = red[t] + red[t + 64];
        for (int m = 32; m; m >>= 1) x += __shfl_xor(x, m, 64);
        if (t == 0) rowsump[v] = x + 1.0f;
    }
}

__global__ __launch_bounds__(256) void colsum_kernel(
    const float* __restrict__ adp, float* __restrict__ colsum) {
    int w = blockIdx.x * 256 + threadIdx.x;
    float s = 0.f;
    for (int v = 0; v < NN; v++) s += adp[v * NN + w];
    colsum[w] = s;
}

// adjacency stored hi/lo split: aT[w][0..511]=hi, aT[w][512..1023]=lo
__global__ __launch_bounds__(256) void normalize_kernel(
    const float* __restrict__ adp, const float* __restrict__ rowsump,
    const float* __restrict__ colsum, unsigned short* __restrict__ a1T,
    unsigned short* __restrict__ a2T) {
    int w = blockIdx.x;
    for (int v = threadIdx.x; v < NN; v += 256) {
        float d = (v == w) ? 1.0f : 0.0f;
        float f1 = (adp[v * NN + w] + d) / rowsump[v];
        float f2 = (adp[w * NN + v] + d) / (colsum[v] + 1.0f);
        unsigned short h1 = f2b(f1), h2 = f2b(f2);
        a1T[w * 1024 + v] = h1;
        a1T[w * 1024 + 512 + v] = f2b(f1 - b2f(h1));
        a2T[w * 1024 + v] = h2;
        a2T[w * 1024 + 512 + v] = f2b(f2 - b2f(h2));
    }
}

// ---------------- main pipeline ----------------
// h storage: [j=(n,c,l)][1024] bf16; cols 0..511 = hi, 512..1023 = lo.

__global__ __launch_bounds__(256) void start_kernel(
    const float* __restrict__ x, const float* __restrict__ sw,
    const float* __restrict__ sb, unsigned int* __restrict__ h_u) {
    int n = blockIdx.x >> 6, l = blockIdx.x & 63;
    int t = threadIdx.x;
    float x0 = x[(n * 512 + 2 * t) * 64 + l];
    float x1 = x[(n * 512 + 2 * t + 1) * 64 + l];
#pragma unroll
    for (int c = 0; c < 32; c++) {
        float wc = sw[c], bc = sb[c];
        float f0 = x0 * wc + bc;
        float f1 = x1 * wc + bc;
        unsigned short h0 = f2b(f0), h1 = f2b(f1);
        float l0 = f0 - b2f(h0), l1 = f1 - b2f(h1);
        int j = (n * 32 + c) * 64 + l;
        h_u[j * 512 + t] = (unsigned int)h0 | ((unsigned int)h1 << 16);
        h_u[j * 512 + 256 + t] = pk2(l0, l1);
    }
}

// Paired propagation: dst1 = 0.05*base + 0.95*A1.src1, dst2 = 0.05*base +
// 0.95*A2.src2 in ONE kernel. SHAREA: src1==src2 (one A stage).
// Compensated K=1536: A''=[h_hi|h_lo|h_hi], B''=[a_hi;a_hi;a_lo].
// BM=128 BN=64 BK=64, grid(64,8), 256 thr, stage->bar->compute->bar.
template <bool SHAREA>
__global__ __launch_bounds__(256, 2) void prop_pair(
    const unsigned short* __restrict__ HA, const unsigned short* __restrict__ HB,
    const unsigned short* __restrict__ base,
    const unsigned short* __restrict__ AT1,
    const unsigned short* __restrict__ AT2,
    unsigned short* __restrict__ dst1, unsigned short* __restrict__ dst2) {
    __shared__ __align__(16) short At1[128 * 64];                 // 16 KB
    __shared__ __align__(16) short At2[SHAREA ? 8 : 128 * 64];    // 16 KB
    __shared__ __align__(16) short Bt1[64 * 64];                  // 8 KB
    __shared__ __align__(16) short Bt2[64 * 64];                  // 8 KB
    int t = threadIdx.x;
    int lane = t & 63;
    int wid = t >> 6;
    int wm = wid >> 1, wn = wid & 1;
    int j0 = blockIdx.x << 7;
    int w0 = blockIdx.y << 6;
    f32x4 acc1[4][2], acc2[4][2];
#pragma unroll
    for (int m = 0; m < 4; m++)
#pragma unroll
        for (int n = 0; n < 2; n++) {
            acc1[m][n] = (f32x4)0.f;
            acc2[m][n] = (f32x4)0.f;
        }
    int l15 = lane & 15;
    int lhi = lane >> 4;
    int rsw = l15 & 7;
    for (int tk = 0; tk < 24; tk++) {
        int kk = tk << 6;
        int ca = (kk < 1024) ? kk : (kk - 1024);  // h col: hi,lo,hi
        int cb = (kk < 512) ? kk : (kk - 512);    // a col: hi,hi,lo
#pragma unroll
        for (int it = 0; it < 4; it++) {
            int slot = it * 256 + t;
            int r = slot >> 3, sl = slot & 7;
            int src = (sl ^ (r & 7)) << 3;
            gload16(HA + (j0 + r) * 1024 + ca + src, &At1[slot * 8]);
            if constexpr (!SHAREA)
                gload16(HB + (j0 + r) * 1024 + ca + src, &At2[slot * 8]);
        }
#pragma unroll
        for (int it = 0; it < 2; it++) {
            int slot = it * 256 + t;
            int r = slot >> 3, sl = slot & 7;
            int src = (sl ^ (r & 7)) << 3;
            gload16(AT1 + (w0 + r) * 1024 + cb + src, &Bt1[slot * 8]);
            gload16(AT2 + (w0 + r) * 1024 + cb + src, &Bt2[slot * 8]);
        }
        __syncthreads();
#pragma unroll
        for (int kh = 0; kh < 2; kh++) {
            int soff = ((kh * 4 + lhi) ^ rsw) << 3;
            short8 a1[4], b1[2], b2[2];
#pragma unroll
            for (int m = 0; m < 4; m++)
                a1[m] =
                    *(const short8*)&At1[(wm * 64 + m * 16 + l15) * 64 + soff];
#pragma unroll
            for (int n = 0; n < 2; n++) {
                b1[n] =
                    *(const short8*)&Bt1[(wn * 32 + n * 16 + l15) * 64 + soff];
                b2[n] =
                    *(const short8*)&Bt2[(wn * 32 + n * 16 + l15) * 64 + soff];
            }
            if constexpr (SHAREA) {
#pragma unroll
                for (int m = 0; m < 4; m++)
#pragma unroll
                    for (int n = 0; n < 2; n++) {
                        acc1[m][n] = __builtin_amdgcn_mfma_f32_16x16x32_bf16(
                            a1[m], b1[n], acc1[m][n], 0, 0, 0);
                        acc2[m][n] = __builtin_amdgcn_mfma_f32_16x16x32_bf16(
                            a1[m], b2[n], acc2[m][n], 0, 0, 0);
                    }
            } else {
                short8 a2[4];
#pragma unroll
                for (int m = 0; m < 4; m++)
                    a2[m] = *(const short8*)&At2[(wm * 64 + m * 16 + l15) * 64 +
                                                 soff];
#pragma unroll
                for (int m = 0; m < 4; m++)
#pragma unroll
                    for (int n = 0; n < 2; n++) {
                        acc1[m][n] = __builtin_amdgcn_mfma_f32_16x16x32_bf16(
                            a1[m], b1[n], acc1[m][n], 0, 0, 0);
                        acc2[m][n] = __builtin_amdgcn_mfma_f32_16x16x32_bf16(
                            a2[m], b2[n], acc2[m][n], 0, 0, 0);
                    }
            }
        }
        __syncthreads();
    }
    // C/D: col = lane&15, row = (lane>>4)*4 + reg
#pragma unroll
    for (int m = 0; m < 4; m++) {
#pragma unroll
        for (int n = 0; n < 2; n++) {
#pragma unroll
            for (int r = 0; r < 4; r++) {
                int row = j0 + wm * 64 + m * 16 + lhi * 4 + r;
                int col = w0 + wn * 32 + n * 16 + l15;
                int ih = row * 1024 + col;
                float bf = b2f(base[ih]) + b2f(base[ih + 512]);
                float f1 = 0.05f * bf + 0.95f * acc1[m][n][r];
                float f2 = 0.05f * bf + 0.95f * acc2[m][n][r];
                unsigned short h1 = f2b(f1);
                unsigned short h2 = f2b(f2);
                dst1[ih] = h1;
                dst1[ih + 512] = f2b(f1 - b2f(h1));
                dst2[ih] = h2;
                dst2[ih + 512] = f2b(f2 - b2f(h2));
            }
        }
    }
}

// dual chanmix: dst = mix(w1; h0,p1a,p2a) + mix(w2; h0,p1b,p2b), f32-summed.
__global__ __launch_bounds__(256) void chanmix_dual(
    const unsigned int* __restrict__ h0, const unsigned int* __restrict__ p1a,
    const unsigned int* __restrict__ p2a, const unsigned int* __restrict__ p1b,
    const unsigned int* __restrict__ p2b, const float* __restrict__ w1,
    const float* __restrict__ b1, const float* __restrict__ w2,
    const float* __restrict__ b2, unsigned int* __restrict__ dst_u) {
    __shared__ float w1s[3072], w2s[3072];
    int bid = blockIdx.x;
    int vc = bid & 3, l = (bid >> 2) & 63, n = bid >> 8;
    int t = threadIdx.x;
    int vl = t & 63, q = t >> 6;
    for (int i = t; i < 3072; i += 256) {
        w1s[i] = w1[i];
        w2s[i] = w2[i];
    }
    __syncthreads();
    float acc[8][2];
#pragma unroll
    for (int oo = 0; oo < 8; oo++) {
        float bb = b1[q * 8 + oo] + b2[q * 8 + oo];
        acc[oo][0] = bb;
        acc[oo][1] = bb;
    }
    int uoff = vc * 64 + vl;
    for (int c = 0; c < 32; c++) {
        int j = (n * 32 + c) * 64 + l;
        unsigned int u0h = h0[j * 512 + uoff], u0l = h0[j * 512 + 256 + uoff];
        unsigned int uah = p1a[j * 512 + uoff], ual = p1a[j * 512 + 256 + uoff];
        unsigned int ubh = p2a[j * 512 + uoff], ubl = p2a[j * 512 + 256 + uoff];
        unsigned int uch = p1b[j * 512 + uoff], ucl = p1b[j * 512 + 256 + uoff];
        unsigned int udh = p2b[j * 512 + uoff], udl = p2b[j * 512 + 256 + uoff];
        float x0l = ulo(u0h) + ulo(u0l), x0h = uhi(u0h) + uhi(u0l);
        float xal = ulo(uah) + ulo(ual), xah = uhi(uah) + uhi(ual);
        float xbl = ulo(ubh) + ulo(ubl), xbh = uhi(ubh) + uhi(ubl);
        float xcl = ulo(uch) + ulo(ucl), xch = uhi(uch) + uhi(ucl);
        float xdl = ulo(udh) + ulo(udl), xdh = uhi(udh) + uhi(udl);
#pragma unroll
        for (int oo = 0; oo < 8; oo++) {
            int o = q * 8 + oo;
            float wa0 = w1s[o * 96 + c];
            float wa1 = w1s[o * 96 + 32 + c];
            float wa2 = w1s[o * 96 + 64 + c];
            float wb0 = w2s[o * 96 + c];
            float wb1 = w2s[o * 96 + 32 + c];
            float wb2 = w2s[o * 96 + 64 + c];
            acc[oo][0] += x0l * wa0 + xal * wa1 + xbl * wa2 + x0l * wb0 +
                          xcl * wb1 + xdl * wb2;
            acc[oo][1] += x0h * wa0 + xah * wa1 + xbh * wa2 + x0h * wb0 +
                          xch * wb1 + xdh * wb2;
        }
    }
#pragma unroll
    for (int oo = 0; oo < 8; oo++) {
        int o = q * 8 + oo;
        int j = (n * 32 + o) * 64 + l;
        float a0 = acc[oo][0], a1 = acc[oo][1];
        unsigned short hi0 = f2b(a0), hi1 = f2b(a1);
        dst_u[j * 512 + uoff] = (unsigned int)hi0 | ((unsigned int)hi1 << 16);
        dst_u[j * 512 + 256 + uoff] = pk2(a0 - b2f(hi0), a1 - b2f(hi1));
    }
}

// LayerNorm#1 (over l) + transpose to v-major: ht[(n*512+v)][c*64+l] packed
// uint32 (hi | lo<<16). grid = n(4) x c(32) x vb(8) = 1024 blocks, 256 thr.
__global__ __launch_bounds__(256) void lnt_kernel(
    const unsigned short* __restrict__ h, const float* __restrict__ lw,
    const float* __restrict__ lb, unsigned int* __restrict__ ht) {
    __shared__ float th[64][65];
    __shared__ unsigned int tt[64][65];
    __shared__ float p1s[4][64], p2s[4][64], ms[64], is[64];
    int b = blockIdx.x;
    int c = b & 31, vb = (b >> 5) & 7, n = b >> 8;
    int t = threadIdx.x;
#pragma unroll
    for (int half = 0; half < 2; half++) {
        int s = half * 256 + t;
        int l = s >> 3, q = s & 7;
        const unsigned short* p =
            h + (size_t)((n * 32 + c) * 64 + l) * 1024 + vb * 64 + q * 8;
        short8 hiv = *(const short8*)p;
        short8 lov = *(const short8*)(p + 512);
#pragma unroll
        for (int i = 0; i < 8; i++)
            th[l][q * 8 + i] =
                b2f((unsigned short)hiv[i]) + b2f((unsigned short)lov[i]);
    }
    __syncthreads();
    {
        int v = t & 63, g = t >> 6;
        float s = 0.f, sq = 0.f;
#pragma unroll
        for (int i = 0; i < 16; i++) {
            float f = th[g * 16 + i][v];
            s += f;
            sq += f * f;
        }
        p1s[g][v] = s;
        p2s[g][v] = sq;
    }
    __syncthreads();
    if (t < 64) {
        float s = p1s[0][t] + p1s[1][t] + p1s[2][t] + p1s[3][t];
        float sq = p2s[0][t] + p2s[1][t] + p2s[2][t] + p2s[3][t];
        float m = s * (1.f / 64.f);
        float var = fmaxf(sq * (1.f / 64.f) - m * m, 0.f);
        ms[t] = m;
        is[t] = 1.f / sqrtf(var + 1e-12f);
    }
    __syncthreads();
    {
        int v = t & 63, g = t >> 6;
        float m = ms[v], inv = is[v];
#pragma unroll
        for (int i = 0; i < 16; i++) {
            int l = g * 16 + i;
            float f = lw[l] * (th[l][v] - m) * inv + lb[l];
            unsigned short hi = f2b(f);
            tt[v][l] = (unsigned int)hi | ((unsigned int)f2b(f - b2f(hi)) << 16);
        }
    }
    __syncthreads();
    {
        int vr = t >> 2, ch = t & 3;
        unsigned int* dstp =
            ht + (size_t)(n * 512 + vb * 64 + vr) * 2048 + c * 64 + ch * 16;
#pragma unroll
        for (int i = 0; i < 4; i++) {
            uint4 val;
            val.x = tt[vr][ch * 16 + i * 4 + 0];
            val.y = tt[vr][ch * 16 + i * 4 + 1];
            val.z = tt[vr][ch * 16 + i * 4 + 2];
            val.w = tt[vr][ch * 16 + i * 4 + 3];
            *(uint4*)(dstp + i * 4) = val;
        }
    }
}

// fused end1+selu+end2+LN#2+sum. One wave per (n,v); 512 blocks x 256 thr.
// (256,2): VGPR cap 256 so hv[32]+e1[64] stay in registers (no spill).
__global__ __launch_bounds__(256, 2) void end_fused2(
    const unsigned int* __restrict__ ht, const float* __restrict__ w1,
    const float* __restrict__ b1, const float* __restrict__ w2,
    const float* __restrict__ b2, const float* __restrict__ lw,
    const float* __restrict__ lb, float* __restrict__ out) {
    __shared__ float w1s[64 * 32];  // [o1][c]  8 KB
    __shared__ float w2s[64 * 64];  // [o2][o1] 16 KB
    __shared__ float b1s[64], b2s[64], lws[64], lbs[64];
    int t = threadIdx.x;
    for (int i = t; i < 2048; i += 256) w1s[i] = w1[i];
    for (int i = t; i < 4096; i += 256) w2s[i] = w2[i];
    if (t < 64) {
        b1s[t] = b1[t];
        b2s[t] = b2[t];
        lws[t] = lw[t];
        lbs[t] = lb[t];
    }
    __syncthreads();
    int wid = t >> 6, lane = t & 63;
    int gw = blockIdx.x * 4 + wid;
    int n = gw >> 9, v = gw & 511;
    const unsigned int* row = ht + (size_t)(n * 512 + v) * 2048;
    float hv[32];
#pragma unroll
    for (int c = 0; c < 32; c++) {
        unsigned int u = row[c * 64 + lane];
        hv[c] = ulo(u) + uhi(u);
    }
    float e1[64];
#pragma unroll
    for (int o1 = 0; o1 < 64; o1++) {
        float a = b1s[o1];
#pragma unroll
        for (int cq = 0; cq < 8; cq++) {
            float4 wv = *(const float4*)&w1s[o1 * 32 + cq * 4];
            a += wv.x * hv[cq * 4] + wv.y * hv[cq * 4 + 1] +
                 wv.z * hv[cq * 4 + 2] + wv.w * hv[cq * 4 + 3];
        }
        e1[o1] = selu_f(a);
    }
    float lwl = lws[lane], lbl = lbs[lane];
    float accout = 0.f;
    for (int o2 = 0; o2 < 64; o2++) {
        float pa = 0.f, pb = 0.f, pc = 0.f, pd = 0.f;
#pragma unroll
        for (int oq = 0; oq < 16; oq++) {
            float4 wv = *(const float4*)&w2s[o2 * 64 + oq * 4];
            pa += wv.x * e1[oq * 4];
            pb += wv.y * e1[oq * 4 + 1];
            pc += wv.z * e1[oq * 4 + 2];
            pd += wv.w * e1[oq * 4 + 3];
        }
        float e2 = b2s[o2] + ((pa + pb) + (pc + pd));
        float sA = e2, sB = e2 * e2;
#pragma unroll
        for (int m = 1; m < 64; m <<= 1) {
            sA += __shfl_xor(sA, m, 64);
            sB += __shfl_xor(sB, m, 64);
        }
        float mean = sA * (1.f / 64.f);
        float var = fmaxf(sB * (1.f / 64.f) - mean * mean, 0.f);
        float inv = 1.f / sqrtf(var + 1e-12f);
        accout += lwl * (e2 - mean) * inv + lbl;
    }
    out[(n * 64 + lane) * 512 + v] = accout;
}

// ---------------- launch ----------------

extern "C" void kernel_launch(void* const* d_in, const int* in_sizes, int n_in,
                              void* d_out, int out_size, void* d_ws,
                              size_t ws_size, hipStream_t stream) {
    const float* x = (const float*)d_in[0];
    const float* emb1 = (const float*)d_in[1];
    const float* emb2 = (const float*)d_in[2];
    const float* lin1_w = (const float*)d_in[3];
    const float* lin1_b = (const float*)d_in[4];
    const float* lin2_w = (const float*)d_in[5];
    const float* lin2_b = (const float*)d_in[6];
    const float* start_w = (const float*)d_in[7];
    const float* start_b = (const float*)d_in[8];
    const float* g1_w = (const float*)d_in[9];
    const float* g1_b = (const float*)d_in[10];
    const float* g2_w = (const float*)d_in[11];
    const float* g2_b = (const float*)d_in[12];
    const float* ln_w = (const float*)d_in[13];
    const float* ln_b = (const float*)d_in[14];
    const float* end1_w = (const float*)d_in[15];
    const float* end1_b = (const float*)d_in[16];
    const float* end2_w = (const float*)d_in[17];
    const float* end2_b = (const float*)d_in[18];
    float* out = (float*)d_out;

    char* ws = (char*)d_ws;
    float* nv1 = (float*)(ws + 0);
    float* nv2 = (float*)(ws + 131072);
    float* adp = (float*)(ws + 262144);                     // 1 MB f32
    unsigned short* a1T = (unsigned short*)(ws + 1310720);  // 1 MB hi/lo
    unsigned short* a2T = (unsigned short*)(ws + 2359296);  // 1 MB hi/lo
    float* rowsump = (float*)(ws + 3407872);
    float* colsum = (float*)(ws + 3409920);
    unsigned short* hA = (unsigned short*)(ws + 4194304);   // 16 MB each
    unsigned short* hB = (unsigned short*)(ws + 20971520);
    unsigned short* s1 = (unsigned short*)(ws + 37748736);
    unsigned short* s2 = (unsigned short*)(ws + 54525952);
    unsigned short* s3 = (unsigned short*)(ws + 71303168);
    unsigned short* s4 = (unsigned short*)(ws + 88080384);  // ends 100 MB

    nodevec_kernel<<<512, 64, 0, stream>>>(emb1, lin1_w, lin1_b, nv1);
    nodevec_kernel<<<512, 64, 0, stream>>>(emb2, lin2_w, lin2_b, nv2);
    adjacency_kernel<<<512, 512, 0, stream>>>(nv1, nv2, adp);
    topk_kernel<<<512, 256, 0, stream>>>(adp, rowsump);
    colsum_kernel<<<2, 256, 0, stream>>>(adp, colsum);
    normalize_kernel<<<512, 256, 0, stream>>>(adp, rowsump, colsum, a1T, a2T);

    start_kernel<<<256, 256, 0, stream>>>(x, start_w, start_b, (unsigned int*)hA);

    dim3 pgrid(64, 8);
    unsigned short* cur = hA;
    unsigned short* nxt = hB;
    for (int layer = 0; layer < 2; layer++) {
        const float* w1 = g1_w + layer * 32 * 96;
        const float* bb1 = g1_b + layer * 32;
        const float* w2 = g2_w + layer * 32 * 96;
        const float* bb2 = g2_b + layer * 32;
        // first hops (shared A): s1 = A1.cur, s2 = A2.cur
        prop_pair<true><<<pgrid, 256, 0, stream>>>(cur, cur, cur, a1T, a2T,
                                                   s1, s2);
        // second hops: s3 = A1.s1, s4 = A2.s2 (base = cur)
        prop_pair<false><<<pgrid, 256, 0, stream>>>(s1, s2, cur, a1T, a2T,
                                                    s3, s4);
        chanmix_dual<<<1024, 256, 0, stream>>>(
            (const unsigned int*)cur, (const unsigned int*)s1,
            (const unsigned int*)s3, (const unsigned int*)s2,
            (const unsigned int*)s4, w1, bb1, w2, bb2, (unsigned int*)nxt);
        unsigned short* tmp = cur;
        cur = nxt;
        nxt = tmp;
    }

    lnt_kernel<<<1024, 256, 0, stream>>>(cur, ln_w, ln_b, (unsigned int*)s1);
    end_fused2<<<512, 256, 0, stream>>>((const unsigned int*)s1, end1_w, end1_b,
                                        end2_w, end2_b, ln_w, ln_b, out);
}

// Round 9
// 429.112 us; speedup vs baseline: 1.2892x; 1.0144x over previous
//
#include <hip/hip_runtime.h>
#include <hip/hip_bf16.h>
#include <math.h>

#define NN 512

typedef __attribute__((ext_vector_type(8))) short short8;
typedef __attribute__((ext_vector_type(4))) float f32x4;

__device__ __forceinline__ float selu_f(float x) {
    const float sc = 1.0507009873554805f, al = 1.6732632423543772f;
    return x > 0.f ? sc * x : sc * al * expm1f(x);
}
__device__ __forceinline__ unsigned short f2b(float f) {
    unsigned int u = __float_as_uint(f);
    unsigned int r = (u + 0x7fffu + ((u >> 16) & 1u)) >> 16;
    return (unsigned short)r;
}
__device__ __forceinline__ float b2f(unsigned short h) {
    return __uint_as_float(((unsigned int)h) << 16);
}
__device__ __forceinline__ float ulo(unsigned int u) {
    return __uint_as_float(u << 16);
}
__device__ __forceinline__ float uhi(unsigned int u) {
    return __uint_as_float(u & 0xffff0000u);
}
__device__ __forceinline__ unsigned int pk2(float a, float b) {
    return (unsigned int)f2b(a) | ((unsigned int)f2b(b) << 16);
}
__device__ __forceinline__ void gload16(const void* g, void* l) {
    __builtin_amdgcn_global_load_lds(
        (const __attribute__((address_space(1))) unsigned int*)g,
        (__attribute__((address_space(3))) unsigned int*)l, 16, 0, 0);
}

// ---------------- graph construction (f32) ----------------

__global__ __launch_bounds__(64) void nodevec_kernel(
    const float* __restrict__ emb, const float* __restrict__ lw,
    const float* __restrict__ lb, float* __restrict__ nv) {
    int i = blockIdx.x, j = threadIdx.x;
    __shared__ float e_s[64];
    e_s[j] = emb[i * 64 + j];
    __syncthreads();
    float acc = lb[j];
    for (int k = 0; k < 64; k++) acc += e_s[k] * lw[j * 64 + k];
    nv[i * 64 + j] = tanhf(3.0f * acc);
}

__global__ __launch_bounds__(512) void adjacency_kernel(
    const float* __restrict__ nv1, const float* __restrict__ nv2,
    float* __restrict__ adj) {
    int v = blockIdx.x, w = threadIdx.x;
    __shared__ float a1s[64], a2s[64];
    if (threadIdx.x < 64) {
        a1s[threadIdx.x] = nv1[v * 64 + threadIdx.x];
        a2s[threadIdx.x] = nv2[v * 64 + threadIdx.x];
    }
    __syncthreads();
    float acc = 0.f;
    for (int k = 0; k < 64; k++) {
        acc += a1s[k] * nv2[w * 64 + k];
        acc -= a2s[k] * nv1[w * 64 + k];
    }
    adj[v * NN + w] = selu_f(tanhf(3.0f * acc));
}

__global__ __launch_bounds__(256) void topk_kernel(
    float* __restrict__ adj, float* __restrict__ rowsump) {
    __shared__ float orig[512], srt[512];
    __shared__ unsigned char keep[512];
    __shared__ float red[256];
    int v = blockIdx.x, t = threadIdx.x;
    orig[t] = adj[v * NN + t];
    orig[t + 256] = adj[v * NN + t + 256];
    srt[t] = orig[t];
    srt[t + 256] = orig[t + 256];
    __syncthreads();
    for (int k = 2; k <= 512; k <<= 1) {
        for (int j = k >> 1; j > 0; j >>= 1) {
            for (int pass = 0; pass < 2; ++pass) {
                int i = t + pass * 256;
                int ixj = i ^ j;
                if (ixj > i) {
                    bool up = ((i & k) == 0);
                    float a = srt[i], b = srt[ixj];
                    if ((a > b) == up) { srt[i] = b; srt[ixj] = a; }
                }
            }
            __syncthreads();
        }
    }
    float thr = srt[256];
    if (t == 0) {
        int g = 0;
        for (int i = 0; i < 512; i++) if (srt[i] > thr) g++;
        int quota = 256 - g;
        for (int w = 0; w < 512; w++) {
            float x = orig[w];
            bool kp = false;
            if (x > thr) kp = true;
            else if (x == thr && quota > 0) { kp = true; quota--; }
            keep[w] = kp ? 1 : 0;
        }
    }
    __syncthreads();
    float part = 0.f;
    for (int pass = 0; pass < 2; pass++) {
        int w = t + pass * 256;
        float val = keep[w] ? orig[w] : 0.0f;
        adj[v * NN + w] = val;
        part += val;
    }
    red[t] = part;
    __syncthreads();
    if (t < 128) red[t] += red[t + 128];
    __syncthreads();
    if (t < 64) {
        float x = red[t] + red[t + 64];
        for (int m = 32; m; m >>= 1) x += __shfl_xor(x, m, 64);
        if (t == 0) rowsump[v] = x + 1.0f;
    }
}

// column-sum phase 1: 16 blocks x 32 rows each, coalesced
__global__ __launch_bounds__(256) void colsum_part(
    const float* __restrict__ adp, float* __restrict__ part) {
    int b = blockIdx.x, w = threadIdx.x;
    float s0 = 0.f, s1 = 0.f;
    for (int r = 0; r < 32; r++) {
        s0 += adp[(b * 32 + r) * 512 + w];
        s1 += adp[(b * 32 + r) * 512 + w + 256];
    }
    part[b * 512 + w] = s0;
    part[b * 512 + w + 256] = s1;
}
__global__ __launch_bounds__(512) void colsum_red(
    const float* __restrict__ part, float* __restrict__ colsum) {
    int w = threadIdx.x;
    float s = 0.f;
    for (int b = 0; b < 16; b++) s += part[b * 512 + w];
    colsum[w] = s;
}

// adjacency stored hi/lo split: aT[w][0..511]=hi, aT[w][512..1023]=lo
__global__ __launch_bounds__(256) void normalize_kernel(
    const float* __restrict__ adp, const float* __restrict__ rowsump,
    const float* __restrict__ colsum, unsigned short* __restrict__ a1T,
    unsigned short* __restrict__ a2T) {
    int w = blockIdx.x;
    for (int v = threadIdx.x; v < NN; v += 256) {
        float d = (v == w) ? 1.0f : 0.0f;
        float f1 = (adp[v * NN + w] + d) / rowsump[v];
        float f2 = (adp[w * NN + v] + d) / (colsum[v] + 1.0f);
        unsigned short h1 = f2b(f1), h2 = f2b(f2);
        a1T[w * 1024 + v] = h1;
        a1T[w * 1024 + 512 + v] = f2b(f1 - b2f(h1));
        a2T[w * 1024 + v] = h2;
        a2T[w * 1024 + 512 + v] = f2b(f2 - b2f(h2));
    }
}

// ---------------- main pipeline ----------------
// h storage: [j=(n,c,l)][1024] bf16; cols 0..511 = hi, 512..1023 = lo.

__global__ __launch_bounds__(256) void start_kernel(
    const float* __restrict__ x, const float* __restrict__ sw,
    const float* __restrict__ sb, unsigned int* __restrict__ h_u) {
    int n = blockIdx.x >> 6, l = blockIdx.x & 63;
    int t = threadIdx.x;
    float x0 = x[(n * 512 + 2 * t) * 64 + l];
    float x1 = x[(n * 512 + 2 * t + 1) * 64 + l];
#pragma unroll
    for (int c = 0; c < 32; c++) {
        float wc = sw[c], bc = sb[c];
        float f0 = x0 * wc + bc;
        float f1 = x1 * wc + bc;
        unsigned short h0 = f2b(f0), h1 = f2b(f1);
        float l0 = f0 - b2f(h0), l1 = f1 - b2f(h1);
        int j = (n * 32 + c) * 64 + l;
        h_u[j * 512 + t] = (unsigned int)h0 | ((unsigned int)h1 << 16);
        h_u[j * 512 + 256 + t] = pk2(l0, l1);
    }
}

// Paired propagation; XCD-chunked block remap (T1): each XCD works a 4 MB
// A-panel x B-panel footprint that fits its private L2.
template <bool SHAREA>
__global__ __launch_bounds__(256, 2) void prop_pair(
    const unsigned short* __restrict__ HA, const unsigned short* __restrict__ HB,
    const unsigned short* __restrict__ base,
    const unsigned short* __restrict__ AT1,
    const unsigned short* __restrict__ AT2,
    unsigned short* __restrict__ dst1, unsigned short* __restrict__ dst2) {
    __shared__ __align__(16) short At1[128 * 64];
    __shared__ __align__(16) short At2[SHAREA ? 8 : 128 * 64];
    __shared__ __align__(16) short Bt1[64 * 64];
    __shared__ __align__(16) short Bt2[64 * 64];
    int t = threadIdx.x;
    int lane = t & 63;
    int wid = t >> 6;
    int wm = wid >> 1, wn = wid & 1;
    // XCD-chunked remap: flat id (x fastest) -> contiguous chunk per XCD.
    int flat = blockIdx.y * 64 + blockIdx.x;     // 0..511
    int wid_ = (flat & 7) * 64 + (flat >> 3);    // chunk of 64 per XCD
    int local = wid_ & 63;
    int j0 = (((wid_ >> 6) << 3) + (local & 7)) << 7;  // j-block *128
    int w0 = (local >> 3) << 6;                        // w-block *64
    f32x4 acc1[4][2], acc2[4][2];
#pragma unroll
    for (int m = 0; m < 4; m++)
#pragma unroll
        for (int n = 0; n < 2; n++) {
            acc1[m][n] = (f32x4)0.f;
            acc2[m][n] = (f32x4)0.f;
        }
    int l15 = lane & 15;
    int lhi = lane >> 4;
    int rsw = l15 & 7;
    for (int tk = 0; tk < 24; tk++) {
        int kk = tk << 6;
        int ca = (kk < 1024) ? kk : (kk - 1024);
        int cb = (kk < 512) ? kk : (kk - 512);
#pragma unroll
        for (int it = 0; it < 4; it++) {
            int slot = it * 256 + t;
            int r = slot >> 3, sl = slot & 7;
            int src = (sl ^ (r & 7)) << 3;
            gload16(HA + (j0 + r) * 1024 + ca + src, &At1[slot * 8]);
            if constexpr (!SHAREA)
                gload16(HB + (j0 + r) * 1024 + ca + src, &At2[slot * 8]);
        }
#pragma unroll
        for (int it = 0; it < 2; it++) {
            int slot = it * 256 + t;
            int r = slot >> 3, sl = slot & 7;
            int src = (sl ^ (r & 7)) << 3;
            gload16(AT1 + (w0 + r) * 1024 + cb + src, &Bt1[slot * 8]);
            gload16(AT2 + (w0 + r) * 1024 + cb + src, &Bt2[slot * 8]);
        }
        __syncthreads();
#pragma unroll
        for (int kh = 0; kh < 2; kh++) {
            int soff = ((kh * 4 + lhi) ^ rsw) << 3;
            short8 a1[4], b1[2], b2[2];
#pragma unroll
            for (int m = 0; m < 4; m++)
                a1[m] =
                    *(const short8*)&At1[(wm * 64 + m * 16 + l15) * 64 + soff];
#pragma unroll
            for (int n = 0; n < 2; n++) {
                b1[n] =
                    *(const short8*)&Bt1[(wn * 32 + n * 16 + l15) * 64 + soff];
                b2[n] =
                    *(const short8*)&Bt2[(wn * 32 + n * 16 + l15) * 64 + soff];
            }
            if constexpr (SHAREA) {
#pragma unroll
                for (int m = 0; m < 4; m++)
#pragma unroll
                    for (int n = 0; n < 2; n++) {
                        acc1[m][n] = __builtin_amdgcn_mfma_f32_16x16x32_bf16(
                            a1[m], b1[n], acc1[m][n], 0, 0, 0);
                        acc2[m][n] = __builtin_amdgcn_mfma_f32_16x16x32_bf16(
                            a1[m], b2[n], acc2[m][n], 0, 0, 0);
                    }
            } else {
                short8 a2[4];
#pragma unroll
                for (int m = 0; m < 4; m++)
                    a2[m] = *(const short8*)&At2[(wm * 64 + m * 16 + l15) * 64 +
                                                 soff];
#pragma unroll
                for (int m = 0; m < 4; m++)
#pragma unroll
                    for (int n = 0; n < 2; n++) {
                        acc1[m][n] = __builtin_amdgcn_mfma_f32_16x16x32_bf16(
                            a1[m], b1[n], acc1[m][n], 0, 0, 0);
                        acc2[m][n] = __builtin_amdgcn_mfma_f32_16x16x32_bf16(
                            a2[m], b2[n], acc2[m][n], 0, 0, 0);
                    }
            }
        }
        __syncthreads();
    }
#pragma unroll
    for (int m = 0; m < 4; m++) {
#pragma unroll
        for (int n = 0; n < 2; n++) {
#pragma unroll
            for (int r = 0; r < 4; r++) {
                int row = j0 + wm * 64 + m * 16 + lhi * 4 + r;
                int col = w0 + wn * 32 + n * 16 + l15;
                int ih = row * 1024 + col;
                float bf = b2f(base[ih]) + b2f(base[ih + 512]);
                float f1 = 0.05f * bf + 0.95f * acc1[m][n][r];
                float f2 = 0.05f * bf + 0.95f * acc2[m][n][r];
                unsigned short h1 = f2b(f1);
                unsigned short h2 = f2b(f2);
                dst1[ih] = h1;
                dst1[ih + 512] = f2b(f1 - b2f(h1));
                dst2[ih] = h2;
                dst2[ih + 512] = f2b(f2 - b2f(h2));
            }
        }
    }
}

// dual chanmix (unchanged, passing).
__global__ __launch_bounds__(256) void chanmix_dual(
    const unsigned int* __restrict__ h0, const unsigned int* __restrict__ p1a,
    const unsigned int* __restrict__ p2a, const unsigned int* __restrict__ p1b,
    const unsigned int* __restrict__ p2b, const float* __restrict__ w1,
    const float* __restrict__ b1, const float* __restrict__ w2,
    const float* __restrict__ b2, unsigned int* __restrict__ dst_u) {
    __shared__ float w1s[3072], w2s[3072];
    int bid = blockIdx.x;
    int vc = bid & 3, l = (bid >> 2) & 63, n = bid >> 8;
    int t = threadIdx.x;
    int vl = t & 63, q = t >> 6;
    for (int i = t; i < 3072; i += 256) {
        w1s[i] = w1[i];
        w2s[i] = w2[i];
    }
    __syncthreads();
    float acc[8][2];
#pragma unroll
    for (int oo = 0; oo < 8; oo++) {
        float bb = b1[q * 8 + oo] + b2[q * 8 + oo];
        acc[oo][0] = bb;
        acc[oo][1] = bb;
    }
    int uoff = vc * 64 + vl;
    for (int c = 0; c < 32; c++) {
        int j = (n * 32 + c) * 64 + l;
        unsigned int u0h = h0[j * 512 + uoff], u0l = h0[j * 512 + 256 + uoff];
        unsigned int uah = p1a[j * 512 + uoff], ual = p1a[j * 512 + 256 + uoff];
        unsigned int ubh = p2a[j * 512 + uoff], ubl = p2a[j * 512 + 256 + uoff];
        unsigned int uch = p1b[j * 512 + uoff], ucl = p1b[j * 512 + 256 + uoff];
        unsigned int udh = p2b[j * 512 + uoff], udl = p2b[j * 512 + 256 + uoff];
        float x0l = ulo(u0h) + ulo(u0l), x0h = uhi(u0h) + uhi(u0l);
        float xal = ulo(uah) + ulo(ual), xah = uhi(uah) + uhi(ual);
        float xbl = ulo(ubh) + ulo(ubl), xbh = uhi(ubh) + uhi(ubl);
        float xcl = ulo(uch) + ulo(ucl), xch = uhi(uch) + uhi(ucl);
        float xdl = ulo(udh) + ulo(udl), xdh = uhi(udh) + uhi(udl);
#pragma unroll
        for (int oo = 0; oo < 8; oo++) {
            int o = q * 8 + oo;
            float wa0 = w1s[o * 96 + c];
            float wa1 = w1s[o * 96 + 32 + c];
            float wa2 = w1s[o * 96 + 64 + c];
            float wb0 = w2s[o * 96 + c];
            float wb1 = w2s[o * 96 + 32 + c];
            float wb2 = w2s[o * 96 + 64 + c];
            acc[oo][0] += x0l * wa0 + xal * wa1 + xbl * wa2 + x0l * wb0 +
                          xcl * wb1 + xdl * wb2;
            acc[oo][1] += x0h * wa0 + xah * wa1 + xbh * wa2 + x0h * wb0 +
                          xch * wb1 + xdh * wb2;
        }
    }
#pragma unroll
    for (int oo = 0; oo < 8; oo++) {
        int o = q * 8 + oo;
        int j = (n * 32 + o) * 64 + l;
        float a0 = acc[oo][0], a1 = acc[oo][1];
        unsigned short hi0 = f2b(a0), hi1 = f2b(a1);
        dst_u[j * 512 + uoff] = (unsigned int)hi0 | ((unsigned int)hi1 << 16);
        dst_u[j * 512 + 256 + uoff] = pk2(a0 - b2f(hi0), a1 - b2f(hi1));
    }
}

// LayerNorm#1 + transpose to v-major: ht[(n*512+v)][c*64+l] packed u32.
__global__ __launch_bounds__(256) void lnt_kernel(
    const unsigned short* __restrict__ h, const float* __restrict__ lw,
    const float* __restrict__ lb, unsigned int* __restrict__ ht) {
    __shared__ float th[64][65];
    __shared__ unsigned int tt[64][65];
    __shared__ float p1s[4][64], p2s[4][64], ms[64], is[64];
    int b = blockIdx.x;
    int c = b & 31, vb = (b >> 5) & 7, n = b >> 8;
    int t = threadIdx.x;
#pragma unroll
    for (int half = 0; half < 2; half++) {
        int s = half * 256 + t;
        int l = s >> 3, q = s & 7;
        const unsigned short* p =
            h + (size_t)((n * 32 + c) * 64 + l) * 1024 + vb * 64 + q * 8;
        short8 hiv = *(const short8*)p;
        short8 lov = *(const short8*)(p + 512);
#pragma unroll
        for (int i = 0; i < 8; i++)
            th[l][q * 8 + i] =
                b2f((unsigned short)hiv[i]) + b2f((unsigned short)lov[i]);
    }
    __syncthreads();
    {
        int v = t & 63, g = t >> 6;
        float s = 0.f, sq = 0.f;
#pragma unroll
        for (int i = 0; i < 16; i++) {
            float f = th[g * 16 + i][v];
            s += f;
            sq += f * f;
        }
        p1s[g][v] = s;
        p2s[g][v] = sq;
    }
    __syncthreads();
    if (t < 64) {
        float s = p1s[0][t] + p1s[1][t] + p1s[2][t] + p1s[3][t];
        float sq = p2s[0][t] + p2s[1][t] + p2s[2][t] + p2s[3][t];
        float m = s * (1.f / 64.f);
        float var = fmaxf(sq * (1.f / 64.f) - m * m, 0.f);
        ms[t] = m;
        is[t] = 1.f / sqrtf(var + 1e-12f);
    }
    __syncthreads();
    {
        int v = t & 63, g = t >> 6;
        float m = ms[v], inv = is[v];
#pragma unroll
        for (int i = 0; i < 16; i++) {
            int l = g * 16 + i;
            float f = lw[l] * (th[l][v] - m) * inv + lb[l];
            unsigned short hi = f2b(f);
            tt[v][l] = (unsigned int)hi | ((unsigned int)f2b(f - b2f(hi)) << 16);
        }
    }
    __syncthreads();
    {
        int vr = t >> 2, ch = t & 3;
        unsigned int* dstp =
            ht + (size_t)(n * 512 + vb * 64 + vr) * 2048 + c * 64 + ch * 16;
#pragma unroll
        for (int i = 0; i < 4; i++) {
            uint4 val;
            val.x = tt[vr][ch * 16 + i * 4 + 0];
            val.y = tt[vr][ch * 16 + i * 4 + 1];
            val.z = tt[vr][ch * 16 + i * 4 + 2];
            val.w = tt[vr][ch * 16 + i * 4 + 3];
            *(uint4*)(dstp + i * 4) = val;
        }
    }
}

// fused end1+selu+end2+LN#2+sum. One wave per (n,v); 512 blocks x 256 thr.
// e1 kept bf16-PACKED in 32 u32 regs (halves register state -> no spill);
// bf16-e1 error measured at +0.25 absmax (round 4: passed at 0.309).
__global__ __launch_bounds__(256, 2) void end_fused3(
    const unsigned int* __restrict__ ht, const float* __restrict__ w1,
    const float* __restrict__ b1, const float* __restrict__ w2,
    const float* __restrict__ b2, const float* __restrict__ lw,
    const float* __restrict__ lb, float* __restrict__ out) {
    __shared__ float w1s[64 * 32];  // [o1][c]  8 KB
    __shared__ float w2s[64 * 64];  // [o2][o1] 16 KB
    __shared__ float b1s[64], b2s[64], lws[64], lbs[64];
    int t = threadIdx.x;
    for (int i = t; i < 2048; i += 256) w1s[i] = w1[i];
    for (int i = t; i < 4096; i += 256) w2s[i] = w2[i];
    if (t < 64) {
        b1s[t] = b1[t];
        b2s[t] = b2[t];
        lws[t] = lw[t];
        lbs[t] = lb[t];
    }
    __syncthreads();
    int wid = t >> 6, lane = t & 63;
    int gw = blockIdx.x * 4 + wid;
    int n = gw >> 9, v = gw & 511;
    const unsigned int* row = ht + (size_t)(n * 512 + v) * 2048;
    float hvf[32];
#pragma unroll
    for (int c = 0; c < 32; c++) {
        unsigned int u = row[c * 64 + lane];
        hvf[c] = ulo(u) + uhi(u);
    }
    unsigned int e1p[32];
#pragma unroll
    for (int op = 0; op < 32; op++) {
        float a0 = b1s[2 * op], a1 = b1s[2 * op + 1];
#pragma unroll
        for (int cq = 0; cq < 8; cq++) {
            float4 wa = *(const float4*)&w1s[(2 * op) * 32 + cq * 4];
            float4 wb = *(const float4*)&w1s[(2 * op + 1) * 32 + cq * 4];
            a0 += wa.x * hvf[cq * 4] + wa.y * hvf[cq * 4 + 1] +
                  wa.z * hvf[cq * 4 + 2] + wa.w * hvf[cq * 4 + 3];
            a1 += wb.x * hvf[cq * 4] + wb.y * hvf[cq * 4 + 1] +
                  wb.z * hvf[cq * 4 + 2] + wb.w * hvf[cq * 4 + 3];
        }
        e1p[op] = pk2(selu_f(a0), selu_f(a1));
    }
    float lwl = lws[lane], lbl = lbs[lane];
    float accout = 0.f;
    for (int o2 = 0; o2 < 64; o2++) {
        float pa = 0.f, pb = 0.f;
#pragma unroll
        for (int oq = 0; oq < 16; oq++) {
            float4 wv = *(const float4*)&w2s[o2 * 64 + oq * 4];
            unsigned int u0 = e1p[oq * 2];
            unsigned int u1 = e1p[oq * 2 + 1];
            pa += wv.x * ulo(u0) + wv.z * ulo(u1);
            pb += wv.y * uhi(u0) + wv.w * uhi(u1);
        }
        float e2 = b2s[o2] + (pa + pb);
        float sA = e2, sB = e2 * e2;
#pragma unroll
        for (int m = 1; m < 64; m <<= 1) {
            sA += __shfl_xor(sA, m, 64);
            sB += __shfl_xor(sB, m, 64);
        }
        float mean = sA * (1.f / 64.f);
        float var = fmaxf(sB * (1.f / 64.f) - mean * mean, 0.f);
        float inv = 1.f / sqrtf(var + 1e-12f);
        accout += lwl * (e2 - mean) * inv + lbl;
    }
    out[(n * 64 + lane) * 512 + v] = accout;
}

// ---------------- launch ----------------

extern "C" void kernel_launch(void* const* d_in, const int* in_sizes, int n_in,
                              void* d_out, int out_size, void* d_ws,
                              size_t ws_size, hipStream_t stream) {
    const float* x = (const float*)d_in[0];
    const float* emb1 = (const float*)d_in[1];
    const float* emb2 = (const float*)d_in[2];
    const float* lin1_w = (const float*)d_in[3];
    const float* lin1_b = (const float*)d_in[4];
    const float* lin2_w = (const float*)d_in[5];
    const float* lin2_b = (const float*)d_in[6];
    const float* start_w = (const float*)d_in[7];
    const float* start_b = (const float*)d_in[8];
    const float* g1_w = (const float*)d_in[9];
    const float* g1_b = (const float*)d_in[10];
    const float* g2_w = (const float*)d_in[11];
    const float* g2_b = (const float*)d_in[12];
    const float* ln_w = (const float*)d_in[13];
    const float* ln_b = (const float*)d_in[14];
    const float* end1_w = (const float*)d_in[15];
    const float* end1_b = (const float*)d_in[16];
    const float* end2_w = (const float*)d_in[17];
    const float* end2_b = (const float*)d_in[18];
    float* out = (float*)d_out;

    char* ws = (char*)d_ws;
    float* nv1 = (float*)(ws + 0);
    float* nv2 = (float*)(ws + 131072);
    float* adp = (float*)(ws + 262144);
    unsigned short* a1T = (unsigned short*)(ws + 1310720);
    unsigned short* a2T = (unsigned short*)(ws + 2359296);
    float* rowsump = (float*)(ws + 3407872);
    float* colsum = (float*)(ws + 3409920);
    float* cspart = (float*)(ws + 3412992);  // 32 KB partials
    unsigned short* hA = (unsigned short*)(ws + 4194304);
    unsigned short* hB = (unsigned short*)(ws + 20971520);
    unsigned short* s1 = (unsigned short*)(ws + 37748736);
    unsigned short* s2 = (unsigned short*)(ws + 54525952);
    unsigned short* s3 = (unsigned short*)(ws + 71303168);
    unsigned short* s4 = (unsigned short*)(ws + 88080384);

    nodevec_kernel<<<512, 64, 0, stream>>>(emb1, lin1_w, lin1_b, nv1);
    nodevec_kernel<<<512, 64, 0, stream>>>(emb2, lin2_w, lin2_b, nv2);
    adjacency_kernel<<<512, 512, 0, stream>>>(nv1, nv2, adp);
    topk_kernel<<<512, 256, 0, stream>>>(adp, rowsump);
    colsum_part<<<16, 256, 0, stream>>>(adp, cspart);
    colsum_red<<<1, 512, 0, stream>>>(cspart, colsum);
    normalize_kernel<<<512, 256, 0, stream>>>(adp, rowsump, colsum, a1T, a2T);

    start_kernel<<<256, 256, 0, stream>>>(x, start_w, start_b, (unsigned int*)hA);

    dim3 pgrid(64, 8);
    unsigned short* cur = hA;
    unsigned short* nxt = hB;
    for (int layer = 0; layer < 2; layer++) {
        const float* w1 = g1_w + layer * 32 * 96;
        const float* bb1 = g1_b + layer * 32;
        const float* w2 = g2_w + layer * 32 * 96;
        const float* bb2 = g2_b + layer * 32;
        prop_pair<true><<<pgrid, 256, 0, stream>>>(cur, cur, cur, a1T, a2T,
                                                   s1, s2);
        prop_pair<false><<<pgrid, 256, 0, stream>>>(s1, s2, cur, a1T, a2T,
                                                    s3, s4);
        chanmix_dual<<<1024, 256, 0, stream>>>(
            (const unsigned int*)cur, (const unsigned int*)s1,
            (const unsigned int*)s3, (const unsigned int*)s2,
            (const unsigned int*)s4, w1, bb1, w2, bb2, (unsigned int*)nxt);
        unsigned short* tmp = cur;
        cur = nxt;
        nxt = tmp;
    }

    lnt_kernel<<<1024, 256, 0, stream>>>(cur, ln_w, ln_b, (unsigned int*)s1);
    end_fused3<<<512, 256, 0, stream>>>((const unsigned int*)s1, end1_w,
                                        end1_b, end2_w, end2_b, ln_w, ln_b,
                                        out);
}